// Round 3
// baseline (202.515 us; speedup 1.0000x reference)
//
#include <hip/hip_runtime.h>

// GroupConv2D: NHWC, B=32, H=W=56, Cin=Cout=256, groups=8 (32 ch/group), 3x3 SAME.
// Implicit-GEMM per group: M=pixels, N=32(co), K=288 (9 taps x 32 ci).
// mfma_f32_16x16x32_bf16: one K-step == one (ky,kx) tap, 8 contiguous ci per lane.
//
// R3 changes vs R2 (74 us, Occ 33%, MfmaUtil 7.5%, VALU 14% -- still latency-bound):
//  1. Staging fully software-pipelined: unrolled load-all phase (20 dwordx4 in
//     flight per thread) then convert+ds_write phase. R2's dependent
//     load->convert->write loop exposed ~19 HBM round-trips per block (VGPR=64
//     proved nothing was kept in flight).
//  2. Epilogue: per-wave LDS transpose (stride-36, 2-way-conflict-free = free) then
//     14 dwordx4 stores/thread (128B segments) instead of 56 scalar dword stores.
//  3. Grid reordered (g fastest) so rt-neighbors sharing halo rows land on the
//     same XCD L2.
// Floor: ~162 MB HBM @6.3 TB/s ~= 26 us.

#define TPW 7                // 16-pixel tiles per wave (28 tiles / 4 waves)

typedef __bf16 bf16x8 __attribute__((ext_vector_type(8)));
typedef float floatx4 __attribute__((ext_vector_type(4)));
typedef unsigned short ushortx8 __attribute__((ext_vector_type(8)));

__device__ __forceinline__ unsigned short f2bf(float f) {
    unsigned int u = __builtin_bit_cast(unsigned int, f);
    u += 0x7fffu + ((u >> 16) & 1u);           // round-to-nearest-even
    return (unsigned short)(u >> 16);
}

// ---- prep: wgt fp32 [tap][ci][co256] -> ws bf16 [g][tap][co][ci]  (73728 elems)
__global__ __launch_bounds__(256)
void wprep(const float* __restrict__ wgt, unsigned short* __restrict__ wbf) {
    const int i = blockIdx.x * 256 + threadIdx.x;       // grid sized exactly
    const int co256 = i & 255;
    const int tmp   = i >> 8;
    const int ci    = tmp & 31;
    const int kk    = tmp >> 5;                          // 0..8
    const int g  = co256 >> 5;
    const int co = co256 & 31;
    wbf[((g * 9 + kk) * 32 + co) * 32 + ci] = f2bf(wgt[i]);
}

__global__ __launch_bounds__(256, 4)
void gconv_mfma(const float* __restrict__ in, const unsigned short* __restrict__ wbf,
                const float* __restrict__ bias, float* __restrict__ out) {
    const int g  = blockIdx.x;      // 0..7 group   (fastest -> rt-neighbors same XCD)
    const int rt = blockIdx.y;      // 0..6 row-strip
    const int b  = blockIdx.z;      // 0..31 batch
    const int y0 = rt * 8;

    __shared__ unsigned short lds_in[10 * 58 * 32];   // [row][col][ci] bf16, 37120 B

    const int tid = threadIdx.x;

    // ---- stage input halo tile: rows y0-1..y0+8 (10), cols -1..56 (58), 32 ci.
    // Granule = 8 consecutive ci (32 B = 2 float4 loads -> one ds_write_b128).
    // 10*58*4 = 2320 granules; 10 per thread, fully unrolled: ALL loads issued
    // first (MLP ~20 outstanding), then convert+write.
    float4 lo[10], hi[10];
    int ldsoff[10];
#pragma unroll
    for (int i = 0; i < 10; ++i) {
        const int gidx = tid + i * 256;
        const bool valid = gidx < 2320;
        const int sub = gidx & 3;
        const int cr  = gidx >> 2;          // < 580
        const int col = cr % 58;
        const int row = cr / 58;
        const int gy = y0 - 1 + row;
        const int gx = col - 1;
        ldsoff[i] = valid ? (row * 58 + col) * 32 + sub * 8 : -1;
        lo[i] = make_float4(0.f, 0.f, 0.f, 0.f);
        hi[i] = make_float4(0.f, 0.f, 0.f, 0.f);
        if (valid && (unsigned)gy < 56u && (unsigned)gx < 56u) {
            const float* p = &in[(((b * 56 + gy) * 56 + gx) * 256) + g * 32 + sub * 8];
            lo[i] = *reinterpret_cast<const float4*>(p);
            hi[i] = *reinterpret_cast<const float4*>(p + 4);
        }
    }
#pragma unroll
    for (int i = 0; i < 10; ++i) {
        if (ldsoff[i] >= 0) {
            ushortx8 pk;
            pk[0] = f2bf(lo[i].x); pk[1] = f2bf(lo[i].y);
            pk[2] = f2bf(lo[i].z); pk[3] = f2bf(lo[i].w);
            pk[4] = f2bf(hi[i].x); pk[5] = f2bf(hi[i].y);
            pk[6] = f2bf(hi[i].z); pk[7] = f2bf(hi[i].w);
            *reinterpret_cast<ushortx8*>(&lds_in[ldsoff[i]]) = pk;
        }
    }

    __syncthreads();

    const int wv   = tid >> 6;
    const int lane = tid & 63;
    const int lc   = lane & 15;    // A: m-index; B: n-index; C/D: col
    const int quad = lane >> 4;

    // per-lane A base address (ushort units) for each of this wave's 7 pixel tiles
    int lane_base[TPW];
#pragma unroll
    for (int t = 0; t < TPW; ++t) {
        const int p  = (wv * TPW + t) * 16 + lc;     // output pixel 0..447 in strip
        const int yl = p / 56;
        const int xl = p - yl * 56;
        lane_base[t] = (yl * 58 + xl) * 32 + quad * 8;
    }

    // B-fragment base in ws: [g][kk][co][ci] bf16; lane (lc,quad) reads 8 contiguous ci
    const unsigned short* wq = &wbf[((g * 9) * 32) * 32 + quad * 8];  // + (kk*32+co)*32

    floatx4 acc[TPW][2];
#pragma unroll
    for (int t = 0; t < TPW; ++t) {
        acc[t][0] = (floatx4)(0.f);
        acc[t][1] = (floatx4)(0.f);
    }

    // prefetch tap 0's B-fragments
    bf16x8 b0 = *reinterpret_cast<const bf16x8*>(&wq[(0 * 32 + lc) * 32]);
    bf16x8 b1 = *reinterpret_cast<const bf16x8*>(&wq[(0 * 32 + 16 + lc) * 32]);

#pragma unroll
    for (int kk = 0; kk < 9; ++kk) {
        const int ky = kk / 3, kx = kk % 3;
        const int koff = (ky * 58 + kx) * 32;        // wave-uniform tap offset
        bf16x8 nb0 = b0, nb1 = b1;
        if (kk < 8) {   // prefetch next tap (L2-hot) while MFMAs run
            nb0 = *reinterpret_cast<const bf16x8*>(&wq[((kk + 1) * 32 + lc) * 32]);
            nb1 = *reinterpret_cast<const bf16x8*>(&wq[((kk + 1) * 32 + 16 + lc) * 32]);
        }
#pragma unroll
        for (int t = 0; t < TPW; ++t) {
            const bf16x8 a = *reinterpret_cast<const bf16x8*>(&lds_in[lane_base[t] + koff]);
            acc[t][0] = __builtin_amdgcn_mfma_f32_16x16x32_bf16(a, b0, acc[t][0], 0, 0, 0);
            acc[t][1] = __builtin_amdgcn_mfma_f32_16x16x32_bf16(a, b1, acc[t][1], 0, 0, 0);
        }
        b0 = nb0; b1 = nb1;
    }

    // ---- epilogue: per-wave LDS transpose -> coalesced dwordx4 stores.
    // C/D layout: col(co)=lc, row(pixel)=quad*4+r. Scratch [16 px][36 stride] fp32
    // per wave (2-way bank aliasing only = free). Intra-wave: ds_write -> waitcnt
    // -> ds_read, no block barrier needed (one barrier to fence lds_in reuse).
    __syncthreads();
    float* scr = reinterpret_cast<float*>(lds_in) + wv * 576;   // 16*36 floats/wave
    const float bv0 = bias[g * 32 + lc];
    const float bv1 = bias[g * 32 + 16 + lc];
    const int px_s = lane >> 2;          // store-phase pixel 0..15
    const int c8   = (lane & 3) * 8;     // store-phase co offset 0,8,16,24
#pragma unroll
    for (int t = 0; t < TPW; ++t) {
#pragma unroll
        for (int r = 0; r < 4; ++r) {
            const int px = quad * 4 + r;
            scr[px * 36 + lc]      = acc[t][0][r] + bv0;
            scr[px * 36 + 16 + lc] = acc[t][1][r] + bv1;
        }
        asm volatile("s_waitcnt lgkmcnt(0)" ::: "memory");
        const floatx4 oa = *reinterpret_cast<const floatx4*>(&scr[px_s * 36 + c8]);
        const floatx4 ob = *reinterpret_cast<const floatx4*>(&scr[px_s * 36 + c8 + 4]);
        const int p = (wv * TPW + t) * 16 + px_s;
        const int y = p / 56;
        const int x = p - y * 56;
        float* o = &out[(((b * 56) + y0 + y) * 56 + x) * 256 + g * 32 + c8];
        *reinterpret_cast<floatx4*>(o)     = oa;
        *reinterpret_cast<floatx4*>(o + 4) = ob;
        asm volatile("s_waitcnt lgkmcnt(0)" ::: "memory");  // reads done before next overwrite
    }
}

// ---------------- fallback (round-1 kernel, known correct) if ws too small ----
__global__ __launch_bounds__(256, 2)
void gconv_mfma_ldsw(const float* __restrict__ in, const float* __restrict__ wgt,
                     const float* __restrict__ bias, float* __restrict__ out) {
    const int rt = blockIdx.y, g = blockIdx.x, b = blockIdx.z;
    const int y0 = rt * 8;
    __shared__ unsigned short lds_in[10 * 58 * 32];
    __shared__ unsigned short lds_w[9 * 32 * 32];
    const int tid = threadIdx.x;
    for (int i = tid; i < 9 * 32 * 32; i += 256) {
        const int co = i & 31, ci = (i >> 5) & 31, kk = i >> 10;
        lds_w[(kk * 32 + co) * 32 + ci] = f2bf(wgt[(kk * 32 + ci) * 256 + g * 32 + co]);
    }
    for (int c = tid; c < 10 * 58 * 8; c += 256) {
        const int row = c / 464, rem = c - row * 464, col = rem >> 3, q = rem & 7;
        const int gy = y0 - 1 + row, gx = col - 1;
        float4 v = make_float4(0.f, 0.f, 0.f, 0.f);
        if ((unsigned)gy < 56u && (unsigned)gx < 56u)
            v = *reinterpret_cast<const float4*>(&in[(((b * 56 + gy) * 56 + gx) * 256) + g * 32 + q * 4]);
        unsigned short p0 = f2bf(v.x), p1 = f2bf(v.y), p2 = f2bf(v.z), p3 = f2bf(v.w);
        unsigned short* d = &lds_in[(row * 58 + col) * 32 + q * 4];
        d[0] = p0; d[1] = p1; d[2] = p2; d[3] = p3;
    }
    __syncthreads();
    const int wv = tid >> 6, lane = tid & 63, lc = lane & 15, quad = lane >> 4;
    int lane_base[TPW];
#pragma unroll
    for (int t = 0; t < TPW; ++t) {
        const int p = (wv * TPW + t) * 16 + lc;
        const int yl = p / 56, xl = p - yl * 56;
        lane_base[t] = (yl * 58 + xl) * 32 + quad * 8;
    }
    floatx4 acc[TPW][2];
#pragma unroll
    for (int t = 0; t < TPW; ++t) { acc[t][0] = (floatx4)(0.f); acc[t][1] = (floatx4)(0.f); }
#pragma unroll
    for (int kk = 0; kk < 9; ++kk) {
        const int ky = kk / 3, kx = kk % 3;
        const int koff = (ky * 58 + kx) * 32;
        const bf16x8 bf0 = *reinterpret_cast<const bf16x8*>(&lds_w[(kk * 32 + lc) * 32 + quad * 8]);
        const bf16x8 bf1 = *reinterpret_cast<const bf16x8*>(&lds_w[(kk * 32 + 16 + lc) * 32 + quad * 8]);
#pragma unroll
        for (int t = 0; t < TPW; ++t) {
            const bf16x8 a = *reinterpret_cast<const bf16x8*>(&lds_in[lane_base[t] + koff]);
            acc[t][0] = __builtin_amdgcn_mfma_f32_16x16x32_bf16(a, bf0, acc[t][0], 0, 0, 0);
            acc[t][1] = __builtin_amdgcn_mfma_f32_16x16x32_bf16(a, bf1, acc[t][1], 0, 0, 0);
        }
    }
    const float bv0 = bias[g * 32 + lc], bv1 = bias[g * 32 + 16 + lc];
#pragma unroll
    for (int t = 0; t < TPW; ++t)
#pragma unroll
        for (int r = 0; r < 4; ++r) {
            const int p = (wv * TPW + t) * 16 + quad * 4 + r;
            const int y = p / 56, x = p - y * 56;
            float* o = &out[(((b * 56) + y0 + y) * 56 + x) * 256 + g * 32];
            o[lc] = acc[t][0][r] + bv0;
            o[16 + lc] = acc[t][1][r] + bv1;
        }
}

extern "C" void kernel_launch(void* const* d_in, const int* in_sizes, int n_in,
                              void* d_out, int out_size, void* d_ws, size_t ws_size,
                              hipStream_t stream) {
    const float* in   = (const float*)d_in[0];
    const float* wgt  = (const float*)d_in[1];
    const float* bias = (const float*)d_in[2];
    float* out        = (float*)d_out;
    dim3 grid(8, 7, 32);   // (groups, row-strips, batch): g fastest for XCD L2 reuse

    if (ws_size >= (size_t)(8 * 9 * 32 * 32 * sizeof(unsigned short))) {
        unsigned short* wbf = (unsigned short*)d_ws;
        wprep<<<dim3(288, 1, 1), dim3(256, 1, 1), 0, stream>>>(wgt, wbf);
        gconv_mfma<<<grid, dim3(256, 1, 1), 0, stream>>>(in, wbf, bias, out);
    } else {
        gconv_mfma_ldsw<<<grid, dim3(256, 1, 1), 0, stream>>>(in, wgt, bias, out);
    }
}

// Round 4
// 199.515 us; speedup vs baseline: 1.0150x; 1.0150x over previous
//
#include <hip/hip_runtime.h>

// GroupConv2D: NHWC, B=32, H=W=56, Cin=Cout=256, groups=8 (32 ch/group), 3x3 SAME.
// Implicit-GEMM per group: M=pixels, N=32(co), K=288 (9 taps x 32 ci).
// mfma_f32_16x16x32_bf16: one K-step == one (ky,kx) tap, 8 contiguous ci per lane.
//
// R4 change vs R3 (76 us; VGPR=64 proved the compiler rolled the "load-all" MLP
// phase back into dependent batches -- latency still exposed):
//  * Staging now uses __builtin_amdgcn_global_load_lds width=16 (fire-and-forget
//    DMA, cannot be descheduled by the register allocator): fp32 halo tile
//    [10][58][32] = 74,240 B lands in LDS with ~19 outstanding loads/wave.
//  * In-LDS compaction: read-all fp32 to regs (19 float4/thread, barrier-fenced)
//    -> f2bf convert -> ds_write_b64 into front 37 KB as [row][col][ci] bf16.
//    OOB halo pixels (DMA address-clamped) are zeroed here -- no zero-fill pass.
//  * Hot MFMA loop + epilogue identical to verified R3.
//  LDS 74,240 B -> 2 blocks/CU; launch_bounds(256,2) (256-VGPR budget).
// Floor: ~155 MB HBM @6.3 TB/s ~= 25 us.

#define TPW 7                // 16-pixel tiles per wave (28 tiles / 4 waves)

typedef __bf16 bf16x8 __attribute__((ext_vector_type(8)));
typedef float floatx4 __attribute__((ext_vector_type(4)));
typedef unsigned short ushortx4 __attribute__((ext_vector_type(4)));

typedef const __attribute__((address_space(1))) void* gas_ptr;
typedef __attribute__((address_space(3))) void* las_ptr;

__device__ __forceinline__ unsigned short f2bf(float f) {
    unsigned int u = __builtin_bit_cast(unsigned int, f);
    u += 0x7fffu + ((u >> 16) & 1u);           // round-to-nearest-even
    return (unsigned short)(u >> 16);
}

// ---- prep: wgt fp32 [tap][ci][co256] -> ws bf16 [g][tap][co][ci]  (73728 elems)
__global__ __launch_bounds__(256)
void wprep(const float* __restrict__ wgt, unsigned short* __restrict__ wbf) {
    const int i = blockIdx.x * 256 + threadIdx.x;       // grid sized exactly
    const int co256 = i & 255;
    const int tmp   = i >> 8;
    const int ci    = tmp & 31;
    const int kk    = tmp >> 5;                          // 0..8
    const int g  = co256 >> 5;
    const int co = co256 & 31;
    wbf[((g * 9 + kk) * 32 + co) * 32 + ci] = f2bf(wgt[i]);
}

__global__ __launch_bounds__(256, 2)
void gconv_mfma(const float* __restrict__ in, const unsigned short* __restrict__ wbf,
                const float* __restrict__ bias, float* __restrict__ out) {
    const int g  = blockIdx.x;      // 0..7 group   (fastest -> rt-neighbors same XCD)
    const int rt = blockIdx.y;      // 0..6 row-strip
    const int b  = blockIdx.z;      // 0..31 batch
    const int y0 = rt * 8;

    __shared__ float lds_f32[10 * 58 * 32];             // 74,240 B DMA landing zone
    unsigned short* lds_in = reinterpret_cast<unsigned short*>(lds_f32); // bf16 tile (front 37 KB)

    const int tid = threadIdx.x;

    // ---- phase 1: DMA the fp32 halo tile (rows y0-1..y0+8, cols -1..56, 32 ci).
    // 16B chunk c = (pixel<<3)|sub: lds offset c*16 == wave-uniform base + lane*16.
    // OOB halo pixels get a clamped (valid) address; zeroed in phase 3.
#pragma unroll
    for (int r = 0; r < 19; ++r) {
        const int c = tid + r * 256;
        if (c < 4640) {                       // only round 18 is partial (lanes 0-31, wave 0)
            const int px  = c >> 3;
            const int sub = c & 7;
            const int row = px / 58;
            const int col = px - row * 58;
            int gy = y0 - 1 + row;  gy = gy < 0 ? 0 : (gy > 55 ? 55 : gy);
            int gx = col - 1;       gx = gx < 0 ? 0 : (gx > 55 ? 55 : gx);
            const float* gp = &in[(((b * 56 + gy) * 56 + gx) * 256) + g * 32 + sub * 4];
            __builtin_amdgcn_global_load_lds((gas_ptr)gp, (las_ptr)&lds_f32[c * 4], 16, 0, 0);
        }
    }
    __syncthreads();   // vmcnt(0) drain: DMA complete

    // ---- phase 2: read ALL fp32 chunks into registers (barrier-fenced so the
    // in-place overwrite below is race-free and the compiler can't interleave)
    floatx4 v[19];
#pragma unroll
    for (int r = 0; r < 19; ++r) {
        const int c = tid + r * 256;
        if (c < 4640) v[r] = *reinterpret_cast<const floatx4*>(&lds_f32[c * 4]);
    }
    __syncthreads();

    // ---- phase 3: convert+compact to bf16 [row][col][ci] in front 37 KB; zero OOB
#pragma unroll
    for (int r = 0; r < 19; ++r) {
        const int c = tid + r * 256;
        if (c < 4640) {
            const int px  = c >> 3;
            const int row = px / 58;
            const int col = px - row * 58;
            const int gy = y0 - 1 + row;
            const int gx = col - 1;
            const bool ok = ((unsigned)gy < 56u) && ((unsigned)gx < 56u);
            ushortx4 p;
            p[0] = ok ? f2bf(v[r][0]) : (unsigned short)0;
            p[1] = ok ? f2bf(v[r][1]) : (unsigned short)0;
            p[2] = ok ? f2bf(v[r][2]) : (unsigned short)0;
            p[3] = ok ? f2bf(v[r][3]) : (unsigned short)0;
            *reinterpret_cast<ushortx4*>(&lds_in[c * 4]) = p;   // ds_write_b64
        }
    }
    __syncthreads();

    // ---- compute phase (identical to verified R3) ----
    const int wv   = tid >> 6;
    const int lane = tid & 63;
    const int lc   = lane & 15;    // A: m-index; B: n-index; C/D: col
    const int quad = lane >> 4;

    int lane_base[TPW];
#pragma unroll
    for (int t = 0; t < TPW; ++t) {
        const int p  = (wv * TPW + t) * 16 + lc;     // output pixel 0..447 in strip
        const int yl = p / 56;
        const int xl = p - yl * 56;
        lane_base[t] = (yl * 58 + xl) * 32 + quad * 8;
    }

    const unsigned short* wq = &wbf[((g * 9) * 32) * 32 + quad * 8];  // + (kk*32+co)*32

    floatx4 acc[TPW][2];
#pragma unroll
    for (int t = 0; t < TPW; ++t) {
        acc[t][0] = (floatx4)(0.f);
        acc[t][1] = (floatx4)(0.f);
    }

    bf16x8 b0 = *reinterpret_cast<const bf16x8*>(&wq[(0 * 32 + lc) * 32]);
    bf16x8 b1 = *reinterpret_cast<const bf16x8*>(&wq[(0 * 32 + 16 + lc) * 32]);

#pragma unroll
    for (int kk = 0; kk < 9; ++kk) {
        const int ky = kk / 3, kx = kk % 3;
        const int koff = (ky * 58 + kx) * 32;        // wave-uniform tap offset
        bf16x8 nb0 = b0, nb1 = b1;
        if (kk < 8) {   // prefetch next tap (L2-hot) while MFMAs run
            nb0 = *reinterpret_cast<const bf16x8*>(&wq[((kk + 1) * 32 + lc) * 32]);
            nb1 = *reinterpret_cast<const bf16x8*>(&wq[((kk + 1) * 32 + 16 + lc) * 32]);
        }
#pragma unroll
        for (int t = 0; t < TPW; ++t) {
            const bf16x8 a = *reinterpret_cast<const bf16x8*>(&lds_in[lane_base[t] + koff]);
            acc[t][0] = __builtin_amdgcn_mfma_f32_16x16x32_bf16(a, b0, acc[t][0], 0, 0, 0);
            acc[t][1] = __builtin_amdgcn_mfma_f32_16x16x32_bf16(a, b1, acc[t][1], 0, 0, 0);
        }
        b0 = nb0; b1 = nb1;
    }

    // ---- epilogue: per-wave LDS transpose -> coalesced dwordx4 stores (R3-verified)
    __syncthreads();
    float* scr = lds_f32 + wv * 576;   // 16*36 floats/wave
    const float bv0 = bias[g * 32 + lc];
    const float bv1 = bias[g * 32 + 16 + lc];
    const int px_s = lane >> 2;          // store-phase pixel 0..15
    const int c8   = (lane & 3) * 8;     // store-phase co offset 0,8,16,24
#pragma unroll
    for (int t = 0; t < TPW; ++t) {
#pragma unroll
        for (int r = 0; r < 4; ++r) {
            const int px = quad * 4 + r;
            scr[px * 36 + lc]      = acc[t][0][r] + bv0;
            scr[px * 36 + 16 + lc] = acc[t][1][r] + bv1;
        }
        asm volatile("s_waitcnt lgkmcnt(0)" ::: "memory");
        const floatx4 oa = *reinterpret_cast<const floatx4*>(&scr[px_s * 36 + c8]);
        const floatx4 ob = *reinterpret_cast<const floatx4*>(&scr[px_s * 36 + c8 + 4]);
        const int p = (wv * TPW + t) * 16 + px_s;
        const int y = p / 56;
        const int x = p - y * 56;
        float* o = &out[(((b * 56) + y0 + y) * 56 + x) * 256 + g * 32 + c8];
        *reinterpret_cast<floatx4*>(o)     = oa;
        *reinterpret_cast<floatx4*>(o + 4) = ob;
        asm volatile("s_waitcnt lgkmcnt(0)" ::: "memory");  // reads done before next overwrite
    }
}

// ---------------- fallback (round-1 kernel, known correct) if ws too small ----
__global__ __launch_bounds__(256, 2)
void gconv_mfma_ldsw(const float* __restrict__ in, const float* __restrict__ wgt,
                     const float* __restrict__ bias, float* __restrict__ out) {
    const int rt = blockIdx.y, g = blockIdx.x, b = blockIdx.z;
    const int y0 = rt * 8;
    __shared__ unsigned short lds_in[10 * 58 * 32];
    __shared__ unsigned short lds_w[9 * 32 * 32];
    const int tid = threadIdx.x;
    for (int i = tid; i < 9 * 32 * 32; i += 256) {
        const int co = i & 31, ci = (i >> 5) & 31, kk = i >> 10;
        lds_w[(kk * 32 + co) * 32 + ci] = f2bf(wgt[(kk * 32 + ci) * 256 + g * 32 + co]);
    }
    for (int c = tid; c < 10 * 58 * 8; c += 256) {
        const int row = c / 464, rem = c - row * 464, col = rem >> 3, q = rem & 7;
        const int gy = y0 - 1 + row, gx = col - 1;
        float4 v = make_float4(0.f, 0.f, 0.f, 0.f);
        if ((unsigned)gy < 56u && (unsigned)gx < 56u)
            v = *reinterpret_cast<const float4*>(&in[(((b * 56 + gy) * 56 + gx) * 256) + g * 32 + q * 4]);
        unsigned short p0 = f2bf(v.x), p1 = f2bf(v.y), p2 = f2bf(v.z), p3 = f2bf(v.w);
        unsigned short* d = &lds_in[(row * 58 + col) * 32 + q * 4];
        d[0] = p0; d[1] = p1; d[2] = p2; d[3] = p3;
    }
    __syncthreads();
    const int wv = tid >> 6, lane = tid & 63, lc = lane & 15, quad = lane >> 4;
    int lane_base[TPW];
#pragma unroll
    for (int t = 0; t < TPW; ++t) {
        const int p = (wv * TPW + t) * 16 + lc;
        const int yl = p / 56, xl = p - yl * 56;
        lane_base[t] = (yl * 58 + xl) * 32 + quad * 8;
    }
    floatx4 acc[TPW][2];
#pragma unroll
    for (int t = 0; t < TPW; ++t) { acc[t][0] = (floatx4)(0.f); acc[t][1] = (floatx4)(0.f); }
#pragma unroll
    for (int kk = 0; kk < 9; ++kk) {
        const int ky = kk / 3, kx = kk % 3;
        const int koff = (ky * 58 + kx) * 32;
        const bf16x8 bf0 = *reinterpret_cast<const bf16x8*>(&lds_w[(kk * 32 + lc) * 32 + quad * 8]);
        const bf16x8 bf1 = *reinterpret_cast<const bf16x8*>(&lds_w[(kk * 32 + 16 + lc) * 32 + quad * 8]);
#pragma unroll
        for (int t = 0; t < TPW; ++t) {
            const bf16x8 a = *reinterpret_cast<const bf16x8*>(&lds_in[lane_base[t] + koff]);
            acc[t][0] = __builtin_amdgcn_mfma_f32_16x16x32_bf16(a, bf0, acc[t][0], 0, 0, 0);
            acc[t][1] = __builtin_amdgcn_mfma_f32_16x16x32_bf16(a, bf1, acc[t][1], 0, 0, 0);
        }
    }
    const float bv0 = bias[g * 32 + lc], bv1 = bias[g * 32 + 16 + lc];
#pragma unroll
    for (int t = 0; t < TPW; ++t)
#pragma unroll
        for (int r = 0; r < 4; ++r) {
            const int p = (wv * TPW + t) * 16 + quad * 4 + r;
            const int y = p / 56, x = p - y * 56;
            float* o = &out[(((b * 56) + y0 + y) * 56 + x) * 256 + g * 32];
            o[lc] = acc[t][0][r] + bv0;
            o[16 + lc] = acc[t][1][r] + bv1;
        }
}

extern "C" void kernel_launch(void* const* d_in, const int* in_sizes, int n_in,
                              void* d_out, int out_size, void* d_ws, size_t ws_size,
                              hipStream_t stream) {
    const float* in   = (const float*)d_in[0];
    const float* wgt  = (const float*)d_in[1];
    const float* bias = (const float*)d_in[2];
    float* out        = (float*)d_out;
    dim3 grid(8, 7, 32);   // (groups, row-strips, batch): g fastest for XCD L2 reuse

    if (ws_size >= (size_t)(8 * 9 * 32 * 32 * sizeof(unsigned short))) {
        unsigned short* wbf = (unsigned short*)d_ws;
        wprep<<<dim3(288, 1, 1), dim3(256, 1, 1), 0, stream>>>(wgt, wbf);
        gconv_mfma<<<grid, dim3(256, 1, 1), 0, stream>>>(in, wbf, bias, out);
    } else {
        gconv_mfma_ldsw<<<grid, dim3(256, 1, 1), 0, stream>>>(in, wgt, bias, out);
    }
}